// Round 10
// baseline (38.333 us; speedup 1.0000x reference)
//
#include <hip/hip_runtime.h>

// GaussianRenderer: N=512 gaussians -> 256x256x3 f32 image. SINGLE KERNEL
// (producer/consumer fusion — R8's redundant-per-block sort was the mistake;
//  here preprocess is paid ONCE by blocks 0..7, published via device-scope
//  release, consumed by all 512 blocks after an acquire spin).
// Deadlock safety: grid 512 == co-resident capacity (LDS ~60KB -> 2 blk/CU,
// launch_bounds(512,4) caps VGPR at 128); producers never wait on consumers.
// Flag lives in d_ws and is zeroed by a hipMemsetAsync graph node each call.
// Render: 64x2 row-pair tile per block (R7 structure): LDS-staged records,
// exact ellipse-vs-strip cull (eps=1e-7), ballot->compact hit list,
// broadcast-LDS eval feeding both rows, 8 chunk partials merged with the
// associative over operator, coalesced store.

constexpr int   REC   = 16;     // floats per sorted record (64B)
constexpr int   WIMG  = 256;
constexpr int   HIMG  = 256;
constexpr int   SPLIT = 8;
constexpr float LOG2E  = 1.4426950408889634f;
constexpr float INV2PI = 0.15915494309189535f;
constexpr float INVEPS = 1.0e7f;                // 1/eps, eps = 1e-7 cull

__global__ __launch_bounds__(512, 4) void gs_fused(
    const float* __restrict__ means3D, const float* __restrict__ covs3d,
    const float* __restrict__ colors,  const float* __restrict__ opac,
    const float* __restrict__ Km,      const float* __restrict__ Rm,
    const float* __restrict__ tvec,    float* __restrict__ recs,
    unsigned int* __restrict__ flag,   float* __restrict__ out, int N)
{
    // producer-phase LDS
    __shared__ float s_depth[512];
    __shared__ int   s_cnt[64][9];
    // render-phase LDS
    __shared__ float  s_my[512], s_c2[512], s_L2[512], s_c1[512], s_mx[512], s_p0[512];
    __shared__ float  s_ev[512][12];          // 48B rows (16B-aligned)
    __shared__ int    s_hits[SPLIT][64];
    __shared__ float4 s_part[2][SPLIT][64];   // [row][chunk][pixel]
    __shared__ float  s_rgb[2][192];

    const int bid  = (int)blockIdx.x;
    const int t    = threadIdx.x;
    const int nPre = (N + 63) / 64;           // 8 producer blocks

    // ================= producer phase (blocks 0..nPre-1) =================
    if (bid < nPre) {
        const int l  = t & 63, p = t >> 6;
        const int gi = bid * 64 + l;

        float d_all = 3.0e38f;
        if (t < N) {
            const float m0 = means3D[t*3+0], m1 = means3D[t*3+1], m2 = means3D[t*3+2];
            d_all = fmaxf(Rm[6]*m0 + Rm[7]*m1 + Rm[8]*m2 + tvec[2], 1.0f);
        }
        s_depth[t] = d_all;
        __syncthreads();

        // 8-way split stable rank partial for gaussian gi
        const float dg = s_depth[gi & 511];
        int cnt = 0;
        #pragma unroll 16
        for (int j = p*64; j < p*64 + 64; ++j) {
            const float dj = s_depth[j];
            cnt += (dj < dg) || (dj == dg && j < gi);
        }
        s_cnt[l][p] = cnt;

        // heavy per-gaussian math on p==0 threads
        float rec[13];
        const bool act = (p == 0) && (gi < N);
        if (act) {
            float Kl[9], Rl[9], tl[3];
            #pragma unroll
            for (int k = 0; k < 9; ++k) { Kl[k] = Km[k]; Rl[k] = Rm[k]; }
            tl[0] = tvec[0]; tl[1] = tvec[1]; tl[2] = tvec[2];

            const float m0 = means3D[gi*3+0], m1 = means3D[gi*3+1], m2 = means3D[gi*3+2];
            const float cam0 = Rl[0]*m0 + Rl[1]*m1 + Rl[2]*m2 + tl[0];
            const float cam1 = Rl[3]*m0 + Rl[4]*m1 + Rl[5]*m2 + tl[1];
            const float cam2 = Rl[6]*m0 + Rl[7]*m1 + Rl[8]*m2 + tl[2];
            const float Z = cam2;
            const float depth = fmaxf(Z, 1.0f);

            const float s0 = Kl[0]*cam0 + Kl[1]*cam1 + Kl[2]*cam2;
            const float s1 = Kl[3]*cam0 + Kl[4]*cam1 + Kl[5]*cam2;
            const float s2 = Kl[6]*cam0 + Kl[7]*cam1 + Kl[8]*cam2;
            const float mx = s0 / s2, my = s1 / s2;

            const float fx = Kl[0], fy = Kl[4];
            const float iz = 1.0f / Z;
            float J[2][3];
            J[0][0] = fx*iz; J[0][1] = 0.0f;  J[0][2] = -fx*cam0*iz*iz;
            J[1][0] = 0.0f;  J[1][1] = fy*iz; J[1][2] = -fy*cam1*iz*iz;

            float S[9];
            #pragma unroll
            for (int k = 0; k < 9; ++k) S[k] = covs3d[gi*9+k];

            float RS[9], Cc[9];
            #pragma unroll
            for (int r = 0; r < 3; ++r)
                #pragma unroll
                for (int c = 0; c < 3; ++c)
                    RS[r*3+c] = Rl[r*3+0]*S[0+c] + Rl[r*3+1]*S[3+c] + Rl[r*3+2]*S[6+c];
            #pragma unroll
            for (int r = 0; r < 3; ++r)
                #pragma unroll
                for (int c = 0; c < 3; ++c)
                    Cc[r*3+c] = RS[r*3+0]*Rl[c*3+0] + RS[r*3+1]*Rl[c*3+1] + RS[r*3+2]*Rl[c*3+2];

            float JC[2][3];
            #pragma unroll
            for (int r = 0; r < 2; ++r)
                #pragma unroll
                for (int c = 0; c < 3; ++c)
                    JC[r][c] = J[r][0]*Cc[0+c] + J[r][1]*Cc[3+c] + J[r][2]*Cc[6+c];

            const float c200 = JC[0][0]*J[0][0] + JC[0][1]*J[0][1] + JC[0][2]*J[0][2] + 1e-4f;
            const float c201 = JC[0][0]*J[1][0] + JC[0][1]*J[1][1] + JC[0][2]*J[1][2];
            const float c210 = JC[1][0]*J[0][0] + JC[1][1]*J[0][1] + JC[1][2]*J[0][2];
            const float c211 = JC[1][0]*J[1][0] + JC[1][1]*J[1][1] + JC[1][2]*J[1][2] + 1e-4f;

            const float det  = c200*c211 - c201*c210;
            const float idet = 1.0f / det;
            const float ia   = c211*idet;                    // P00
            const float i01  = -0.5f*(c201 + c210)*idet;     // P01 (symmetrized)
            const float ic   = c200*idet;                    // P11
            const float ibs  = 2.0f*i01;

            const bool  valid = (depth > 1.0f) && (depth < 50.0f);
            const float nrm   = valid ? (INV2PI / sqrtf(det)) : 0.0f;
            const float opn   = opac[gi] * nrm;

            // Exact support test params: Q = ia*(dx+c1*dy)^2 + c2*dy^2 <= L2
            const float c1 = i01 / ia;
            const float c2 = ic - i01*i01/ia;
            const float L2 = 2.0f * logf(opn * INVEPS);      // opn<=0 -> -inf

            rec[0]  = my;  rec[1] = c2;  rec[2] = L2;  rec[3] = c1;
            rec[4]  = mx;  rec[5] = ia;
            rec[6]  = -0.5f*LOG2E*ia;    // A
            rec[7]  = -0.5f*LOG2E*ibs;   // B
            rec[8]  = -0.5f*LOG2E*ic;    // C
            rec[9]  = opn;
            rec[10] = colors[gi*3+0];
            rec[11] = colors[gi*3+1];
            rec[12] = colors[gi*3+2];
        }
        __syncthreads();

        if (act) {
            int rank = 0;
            #pragma unroll
            for (int q = 0; q < 8; ++q) rank += s_cnt[l][q];
            float4* dst = (float4*)(recs + rank*REC);
            dst[0] = make_float4(rec[0],  rec[1],  rec[2],  rec[3]);
            dst[1] = make_float4(rec[4],  rec[5],  rec[6],  rec[7]);
            dst[2] = make_float4(rec[8],  rec[9],  rec[10], rec[11]);
            dst[3] = make_float4(rec[12], 0.0f,    0.0f,    0.0f);
        }
        __syncthreads();

        if (t == 0) {
            __threadfence();   // device-scope release of recs stores
            __hip_atomic_fetch_add(flag, 1u, __ATOMIC_RELEASE, __HIP_MEMORY_SCOPE_AGENT);
        }
    }

    // ============== grid-wide consume barrier (acquire spin) ==============
    if (t == 0) {
        while ((int)__hip_atomic_load(flag, __ATOMIC_ACQUIRE, __HIP_MEMORY_SCOPE_AGENT) < nPre)
            __builtin_amdgcn_s_sleep(1);
    }
    __syncthreads();

    // ======================= render phase (all blocks) ====================
    // Stage: thread t handles record t.
    if (t < N) {
        const float4 a = *(const float4*)(recs + t*REC + 0);   // my,c2,L2,c1
        const float4 b = *(const float4*)(recs + t*REC + 4);   // mx,p00,A,B
        const float4 c = *(const float4*)(recs + t*REC + 8);   // C,opn,r,g
        const float4 d = *(const float4*)(recs + t*REC + 12);  // b,-,-,-
        s_my[t] = a.x; s_c2[t] = a.y; s_L2[t] = a.z; s_c1[t] = a.w;
        s_mx[t] = b.x; s_p0[t] = b.y;
        float4* ev = (float4*)s_ev[t];
        ev[0] = make_float4(b.x, a.x, b.z, b.w);   // mx, my, A, B
        ev[1] = make_float4(c.x, c.y, c.z, c.w);   // C, opn, r, g
        s_ev[t][8] = d.x;                          // blue
    } else {
        s_my[t] = 0.0f; s_c2[t] = 0.0f; s_L2[t] = -1e30f;
        s_c1[t] = 0.0f; s_mx[t] = 0.0f; s_p0[t] = 1.0f;
    }
    __syncthreads();

    const int w    = t >> 6;
    const int lane = t & 63;
    const int xs   = bid & 3;
    const int pr   = bid >> 2;                         // row pair 0..127
    const float y0f = (float)(2*pr);
    const float sx0 = (float)(xs * 64);
    const float scx = sx0 + 31.5f;                     // strip center x
    const float px  = sx0 + (float)lane;

    // Lane-parallel EXACT ellipse test vs rows {y0, y0+1} for chunk w.
    const int base = w * 64;
    bool hit;
    {
        const int j = base + lane;
        const float myj = s_my[j], c2 = s_c2[j], L2 = s_L2[j];
        const float c1  = s_c1[j], mxj = s_mx[j], p0 = s_p0[j];
        float dy  = y0f - myj;
        float rem = fmaf(-c2, dy*dy, L2);
        float xc  = fmaf(-c1, dy, mxj);
        float t1  = fmaxf(fabsf(xc - scx) - 31.5f, 0.0f);
        const bool h0 = (p0*t1*t1 <= rem);
        dy  = dy + 1.0f;
        rem = fmaf(-c2, dy*dy, L2);
        xc  = xc - c1;
        t1  = fmaxf(fabsf(xc - scx) - 31.5f, 0.0f);
        const bool h1 = (p0*t1*t1 <= rem);
        hit = h0 | h1;
    }
    const unsigned long long mask = __ballot(hit);
    const int nhit = __popcll(mask);
    if (hit) {
        const int pos = __popcll(mask & ((1ull << lane) - 1ull));
        s_hits[w][pos] = base + lane;     // ascending = sorted depth order
    }
    // s_hits[w] written & read by the same wave only: no barrier needed.

    float T0 = 1.0f, r0 = 0.0f, g0 = 0.0f, b0 = 0.0f;
    float T1 = 1.0f, r1 = 0.0f, g1 = 0.0f, b1 = 0.0f;

    for (int i = 0; i < nhit; ++i) {
        const int j = s_hits[w][i];                  // broadcast read
        const float* e = s_ev[j];                    // broadcast rows
        const float4 v0 = *(const float4*)(e + 0);   // mx,my,A,B
        const float4 v1 = *(const float4*)(e + 4);   // C,opn,r,g
        const float  bl = e[8];

        const float dx   = px - v0.x;
        const float adx2 = v0.z * dx * dx;           // A*dx^2 (shared)
        const float u    = v0.w * dx;                // B*dx   (shared)
        const float dy0  = y0f - v0.y;
        const float dy1  = dy0 + 1.0f;
        const float e20  = fmaf(dy0, fmaf(v1.x, dy0, u), adx2);
        const float e21  = fmaf(dy1, fmaf(v1.x, dy1, u), adx2);
        const float al0  = v1.y * __builtin_amdgcn_exp2f(e20);
        const float al1  = v1.y * __builtin_amdgcn_exp2f(e21);

        T0 *= (1.0f - al0);                          // cumprod incl. current
        const float w0 = al0 * T0;
        r0 = fmaf(w0, v1.z, r0); g0 = fmaf(w0, v1.w, g0); b0 = fmaf(w0, bl, b0);

        T1 *= (1.0f - al1);
        const float w1 = al1 * T1;
        r1 = fmaf(w1, v1.z, r1); g1 = fmaf(w1, v1.w, g1); b1 = fmaf(w1, bl, b1);
    }

    s_part[0][w][lane] = make_float4(T0, r0, g0, b0);
    s_part[1][w][lane] = make_float4(T1, r1, g1, b1);
    __syncthreads();

    if (t < 128) {
        const int row = t >> 6, p = t & 63;
        float4 f = s_part[row][0][p];
        float Ta = f.x, r_ = f.y, g_ = f.z, b_ = f.w;
        #pragma unroll
        for (int k = 1; k < SPLIT; ++k) {
            const float4 q = s_part[row][k][p];
            r_ = fmaf(Ta, q.y, r_);
            g_ = fmaf(Ta, q.z, g_);
            b_ = fmaf(Ta, q.w, b_);
            Ta *= q.x;
        }
        s_rgb[row][p*3+0] = r_;
        s_rgb[row][p*3+1] = g_;
        s_rgb[row][p*3+2] = b_;
    }
    __syncthreads();

    if (t < 384) {
        const int row = t / 192, i = t - row * 192;
        out[(2*pr + row) * (WIMG*3) + xs*192 + i] = s_rgb[row][i];
    }
}

extern "C" void kernel_launch(void* const* d_in, const int* in_sizes, int n_in,
                              void* d_out, int out_size, void* d_ws, size_t ws_size,
                              hipStream_t stream)
{
    const float* means3D = (const float*)d_in[0];
    const float* covs3d  = (const float*)d_in[1];
    const float* colors  = (const float*)d_in[2];
    const float* opac    = (const float*)d_in[3];
    const float* Km      = (const float*)d_in[4];
    const float* Rm      = (const float*)d_in[5];
    const float* tv      = (const float*)d_in[6];
    const int N = in_sizes[3];               // opacities: (N,)

    float*        recs = (float*)d_ws;                            // 32 KB
    unsigned int* flag = (unsigned int*)((char*)d_ws + 64*1024);  // own line

    hipMemsetAsync(flag, 0, sizeof(unsigned int), stream);        // graph node

    gs_fused<<<dim3(WIMG * HIMG / 128), dim3(512), 0, stream>>>(
        means3D, covs3d, colors, opac, Km, Rm, tv,
        recs, flag, (float*)d_out, N);
}

// Round 11
// 23.628 us; speedup vs baseline: 1.6223x; 1.6223x over previous
//
#include <hip/hip_runtime.h>

// GaussianRenderer: N=512 gaussians -> 256x256x3 f32 image. SINGLE KERNEL,
// producer/consumer fusion with LOW-CONTENTION sync (R10 post-mortem: per-poll
// ACQUIRE loads caused an L2-invalidate storm; threadfence doubled writebacks).
//   - blocks 0..7 preprocess all N gaussians ONCE (depth, conic, exact-cull
//     params, stable depth-rank) -> recs in d_ws, then RELEASE fetch_add flag
//     (single L2 writeback per producer).
//   - all 512 blocks spin on flag with RELAXED loads + s_sleep backoff, then
//     ONE acquire load, then render their 64x2 tile (R7 structure).
// Deadlock-safe: grid 512 == co-resident capacity (LDS ~60KB -> 2 blk/CU,
// launch_bounds(512,4)); producers never wait on consumers.
// Flag zeroed per call by a hipMemsetAsync graph node.

constexpr int   REC   = 16;     // floats per sorted record (64B)
constexpr int   WIMG  = 256;
constexpr int   HIMG  = 256;
constexpr int   SPLIT = 8;
constexpr float LOG2E  = 1.4426950408889634f;
constexpr float INV2PI = 0.15915494309189535f;
constexpr float INVEPS = 1.0e7f;                // 1/eps, eps = 1e-7 cull

__global__ __launch_bounds__(512, 4) void gs_fused(
    const float* __restrict__ means3D, const float* __restrict__ covs3d,
    const float* __restrict__ colors,  const float* __restrict__ opac,
    const float* __restrict__ Km,      const float* __restrict__ Rm,
    const float* __restrict__ tvec,    float* __restrict__ recs,
    unsigned int* __restrict__ flag,   float* __restrict__ out, int N)
{
    // producer-phase LDS
    __shared__ float s_depth[512];
    __shared__ int   s_cnt[64][9];
    // render-phase LDS
    __shared__ float  s_my[512], s_c2[512], s_L2[512], s_c1[512], s_mx[512], s_p0[512];
    __shared__ float  s_ev[512][12];          // 48B rows (16B-aligned)
    __shared__ int    s_hits[SPLIT][64];
    __shared__ float4 s_part[2][SPLIT][64];   // [row][chunk][pixel]
    __shared__ float  s_rgb[2][192];

    const int bid  = (int)blockIdx.x;
    const int t    = threadIdx.x;
    const int nPre = (N + 63) / 64;           // 8 producer blocks

    // ================= producer phase (blocks 0..nPre-1) =================
    if (bid < nPre) {
        const int l  = t & 63, p = t >> 6;
        const int gi = bid * 64 + l;

        float d_all = 3.0e38f;
        if (t < N) {
            const float m0 = means3D[t*3+0], m1 = means3D[t*3+1], m2 = means3D[t*3+2];
            d_all = fmaxf(Rm[6]*m0 + Rm[7]*m1 + Rm[8]*m2 + tvec[2], 1.0f);
        }
        s_depth[t] = d_all;
        __syncthreads();

        // 8-way split stable rank partial for gaussian gi
        const float dg = s_depth[gi & 511];
        int cnt = 0;
        #pragma unroll 16
        for (int j = p*64; j < p*64 + 64; ++j) {
            const float dj = s_depth[j];
            cnt += (dj < dg) || (dj == dg && j < gi);
        }
        s_cnt[l][p] = cnt;

        // heavy per-gaussian math on p==0 threads
        float rec[13];
        const bool act = (p == 0) && (gi < N);
        if (act) {
            float Kl[9], Rl[9], tl[3];
            #pragma unroll
            for (int k = 0; k < 9; ++k) { Kl[k] = Km[k]; Rl[k] = Rm[k]; }
            tl[0] = tvec[0]; tl[1] = tvec[1]; tl[2] = tvec[2];

            const float m0 = means3D[gi*3+0], m1 = means3D[gi*3+1], m2 = means3D[gi*3+2];
            const float cam0 = Rl[0]*m0 + Rl[1]*m1 + Rl[2]*m2 + tl[0];
            const float cam1 = Rl[3]*m0 + Rl[4]*m1 + Rl[5]*m2 + tl[1];
            const float cam2 = Rl[6]*m0 + Rl[7]*m1 + Rl[8]*m2 + tl[2];
            const float Z = cam2;
            const float depth = fmaxf(Z, 1.0f);

            const float s0 = Kl[0]*cam0 + Kl[1]*cam1 + Kl[2]*cam2;
            const float s1 = Kl[3]*cam0 + Kl[4]*cam1 + Kl[5]*cam2;
            const float s2 = Kl[6]*cam0 + Kl[7]*cam1 + Kl[8]*cam2;
            const float mx = s0 / s2, my = s1 / s2;

            const float fx = Kl[0], fy = Kl[4];
            const float iz = 1.0f / Z;
            float J[2][3];
            J[0][0] = fx*iz; J[0][1] = 0.0f;  J[0][2] = -fx*cam0*iz*iz;
            J[1][0] = 0.0f;  J[1][1] = fy*iz; J[1][2] = -fy*cam1*iz*iz;

            float S[9];
            #pragma unroll
            for (int k = 0; k < 9; ++k) S[k] = covs3d[gi*9+k];

            float RS[9], Cc[9];
            #pragma unroll
            for (int r = 0; r < 3; ++r)
                #pragma unroll
                for (int c = 0; c < 3; ++c)
                    RS[r*3+c] = Rl[r*3+0]*S[0+c] + Rl[r*3+1]*S[3+c] + Rl[r*3+2]*S[6+c];
            #pragma unroll
            for (int r = 0; r < 3; ++r)
                #pragma unroll
                for (int c = 0; c < 3; ++c)
                    Cc[r*3+c] = RS[r*3+0]*Rl[c*3+0] + RS[r*3+1]*Rl[c*3+1] + RS[r*3+2]*Rl[c*3+2];

            float JC[2][3];
            #pragma unroll
            for (int r = 0; r < 2; ++r)
                #pragma unroll
                for (int c = 0; c < 3; ++c)
                    JC[r][c] = J[r][0]*Cc[0+c] + J[r][1]*Cc[3+c] + J[r][2]*Cc[6+c];

            const float c200 = JC[0][0]*J[0][0] + JC[0][1]*J[0][1] + JC[0][2]*J[0][2] + 1e-4f;
            const float c201 = JC[0][0]*J[1][0] + JC[0][1]*J[1][1] + JC[0][2]*J[1][2];
            const float c210 = JC[1][0]*J[0][0] + JC[1][1]*J[0][1] + JC[1][2]*J[0][2];
            const float c211 = JC[1][0]*J[1][0] + JC[1][1]*J[1][1] + JC[1][2]*J[1][2] + 1e-4f;

            const float det  = c200*c211 - c201*c210;
            const float idet = 1.0f / det;
            const float ia   = c211*idet;                    // P00
            const float i01  = -0.5f*(c201 + c210)*idet;     // P01 (symmetrized)
            const float ic   = c200*idet;                    // P11
            const float ibs  = 2.0f*i01;

            const bool  valid = (depth > 1.0f) && (depth < 50.0f);
            const float nrm   = valid ? (INV2PI / sqrtf(det)) : 0.0f;
            const float opn   = opac[gi] * nrm;

            // Exact support test params: Q = ia*(dx+c1*dy)^2 + c2*dy^2 <= L2
            const float c1 = i01 / ia;
            const float c2 = ic - i01*i01/ia;
            const float L2 = 2.0f * logf(opn * INVEPS);      // opn<=0 -> -inf

            rec[0]  = my;  rec[1] = c2;  rec[2] = L2;  rec[3] = c1;
            rec[4]  = mx;  rec[5] = ia;
            rec[6]  = -0.5f*LOG2E*ia;    // A
            rec[7]  = -0.5f*LOG2E*ibs;   // B
            rec[8]  = -0.5f*LOG2E*ic;    // C
            rec[9]  = opn;
            rec[10] = colors[gi*3+0];
            rec[11] = colors[gi*3+1];
            rec[12] = colors[gi*3+2];
        }
        __syncthreads();

        if (act) {
            int rank = 0;
            #pragma unroll
            for (int q = 0; q < 8; ++q) rank += s_cnt[l][q];
            float4* dst = (float4*)(recs + rank*REC);
            dst[0] = make_float4(rec[0],  rec[1],  rec[2],  rec[3]);
            dst[1] = make_float4(rec[4],  rec[5],  rec[6],  rec[7]);
            dst[2] = make_float4(rec[8],  rec[9],  rec[10], rec[11]);
            dst[3] = make_float4(rec[12], 0.0f,    0.0f,    0.0f);
        }
        __syncthreads();

        if (t == 0) {
            // RELEASE add: single L2 writeback makes recs visible device-wide.
            __hip_atomic_fetch_add(flag, 1u, __ATOMIC_RELEASE, __HIP_MEMORY_SCOPE_AGENT);
        }
    }

    // ============== grid-wide consume barrier (low-contention) ============
    if (t == 0) {
        // RELAXED polls: no per-poll L2 invalidate; backoff to limit traffic.
        while (__hip_atomic_load(flag, __ATOMIC_RELAXED, __HIP_MEMORY_SCOPE_AGENT)
               < (unsigned)nPre)
            __builtin_amdgcn_s_sleep(16);
        // ONE acquire to order/invalidate before reading recs.
        (void)__hip_atomic_load(flag, __ATOMIC_ACQUIRE, __HIP_MEMORY_SCOPE_AGENT);
    }
    __syncthreads();

    // ======================= render phase (all blocks) ====================
    // Stage: thread t handles record t.
    if (t < N) {
        const float4 a = *(const float4*)(recs + t*REC + 0);   // my,c2,L2,c1
        const float4 b = *(const float4*)(recs + t*REC + 4);   // mx,p00,A,B
        const float4 c = *(const float4*)(recs + t*REC + 8);   // C,opn,r,g
        const float4 d = *(const float4*)(recs + t*REC + 12);  // b,-,-,-
        s_my[t] = a.x; s_c2[t] = a.y; s_L2[t] = a.z; s_c1[t] = a.w;
        s_mx[t] = b.x; s_p0[t] = b.y;
        float4* ev = (float4*)s_ev[t];
        ev[0] = make_float4(b.x, a.x, b.z, b.w);   // mx, my, A, B
        ev[1] = make_float4(c.x, c.y, c.z, c.w);   // C, opn, r, g
        s_ev[t][8] = d.x;                          // blue
    } else {
        s_my[t] = 0.0f; s_c2[t] = 0.0f; s_L2[t] = -1e30f;
        s_c1[t] = 0.0f; s_mx[t] = 0.0f; s_p0[t] = 1.0f;
    }
    __syncthreads();

    const int w    = t >> 6;
    const int lane = t & 63;
    const int xs   = bid & 3;
    const int pr   = bid >> 2;                         // row pair 0..127
    const float y0f = (float)(2*pr);
    const float sx0 = (float)(xs * 64);
    const float scx = sx0 + 31.5f;                     // strip center x
    const float px  = sx0 + (float)lane;

    // Lane-parallel EXACT ellipse test vs rows {y0, y0+1} for chunk w.
    const int base = w * 64;
    bool hit;
    {
        const int j = base + lane;
        const float myj = s_my[j], c2 = s_c2[j], L2 = s_L2[j];
        const float c1  = s_c1[j], mxj = s_mx[j], p0 = s_p0[j];
        float dy  = y0f - myj;
        float rem = fmaf(-c2, dy*dy, L2);
        float xc  = fmaf(-c1, dy, mxj);
        float t1  = fmaxf(fabsf(xc - scx) - 31.5f, 0.0f);
        const bool h0 = (p0*t1*t1 <= rem);
        dy  = dy + 1.0f;
        rem = fmaf(-c2, dy*dy, L2);
        xc  = xc - c1;
        t1  = fmaxf(fabsf(xc - scx) - 31.5f, 0.0f);
        const bool h1 = (p0*t1*t1 <= rem);
        hit = h0 | h1;
    }
    const unsigned long long mask = __ballot(hit);
    const int nhit = __popcll(mask);
    if (hit) {
        const int pos = __popcll(mask & ((1ull << lane) - 1ull));
        s_hits[w][pos] = base + lane;     // ascending = sorted depth order
    }
    // s_hits[w] written & read by the same wave only: no barrier needed.

    float T0 = 1.0f, r0 = 0.0f, g0 = 0.0f, b0 = 0.0f;
    float T1 = 1.0f, r1 = 0.0f, g1 = 0.0f, b1 = 0.0f;

    for (int i = 0; i < nhit; ++i) {
        const int j = s_hits[w][i];                  // broadcast read
        const float* e = s_ev[j];                    // broadcast rows
        const float4 v0 = *(const float4*)(e + 0);   // mx,my,A,B
        const float4 v1 = *(const float4*)(e + 4);   // C,opn,r,g
        const float  bl = e[8];

        const float dx   = px - v0.x;
        const float adx2 = v0.z * dx * dx;           // A*dx^2 (shared)
        const float u    = v0.w * dx;                // B*dx   (shared)
        const float dy0  = y0f - v0.y;
        const float dy1  = dy0 + 1.0f;
        const float e20  = fmaf(dy0, fmaf(v1.x, dy0, u), adx2);
        const float e21  = fmaf(dy1, fmaf(v1.x, dy1, u), adx2);
        const float al0  = v1.y * __builtin_amdgcn_exp2f(e20);
        const float al1  = v1.y * __builtin_amdgcn_exp2f(e21);

        T0 *= (1.0f - al0);                          // cumprod incl. current
        const float w0 = al0 * T0;
        r0 = fmaf(w0, v1.z, r0); g0 = fmaf(w0, v1.w, g0); b0 = fmaf(w0, bl, b0);

        T1 *= (1.0f - al1);
        const float w1 = al1 * T1;
        r1 = fmaf(w1, v1.z, r1); g1 = fmaf(w1, v1.w, g1); b1 = fmaf(w1, bl, b1);
    }

    s_part[0][w][lane] = make_float4(T0, r0, g0, b0);
    s_part[1][w][lane] = make_float4(T1, r1, g1, b1);
    __syncthreads();

    if (t < 128) {
        const int row = t >> 6, p = t & 63;
        float4 f = s_part[row][0][p];
        float Ta = f.x, r_ = f.y, g_ = f.z, b_ = f.w;
        #pragma unroll
        for (int k = 1; k < SPLIT; ++k) {
            const float4 q = s_part[row][k][p];
            r_ = fmaf(Ta, q.y, r_);
            g_ = fmaf(Ta, q.z, g_);
            b_ = fmaf(Ta, q.w, b_);
            Ta *= q.x;
        }
        s_rgb[row][p*3+0] = r_;
        s_rgb[row][p*3+1] = g_;
        s_rgb[row][p*3+2] = b_;
    }
    __syncthreads();

    if (t < 384) {
        const int row = t / 192, i = t - row * 192;
        out[(2*pr + row) * (WIMG*3) + xs*192 + i] = s_rgb[row][i];
    }
}

extern "C" void kernel_launch(void* const* d_in, const int* in_sizes, int n_in,
                              void* d_out, int out_size, void* d_ws, size_t ws_size,
                              hipStream_t stream)
{
    const float* means3D = (const float*)d_in[0];
    const float* covs3d  = (const float*)d_in[1];
    const float* colors  = (const float*)d_in[2];
    const float* opac    = (const float*)d_in[3];
    const float* Km      = (const float*)d_in[4];
    const float* Rm      = (const float*)d_in[5];
    const float* tv      = (const float*)d_in[6];
    const int N = in_sizes[3];               // opacities: (N,)

    float*        recs = (float*)d_ws;                            // 32 KB
    unsigned int* flag = (unsigned int*)((char*)d_ws + 64*1024);  // own line

    hipMemsetAsync(flag, 0, sizeof(unsigned int), stream);        // graph node

    gs_fused<<<dim3(WIMG * HIMG / 128), dim3(512), 0, stream>>>(
        means3D, covs3d, colors, opac, Km, Rm, tv,
        recs, flag, (float*)d_out, N);
}

// Round 12
// 15.778 us; speedup vs baseline: 2.4295x; 1.4975x over previous
//
#include <hip/hip_runtime.h>

// GaussianRenderer: N=512 gaussians -> 256x256x3 f32 image.  (R7 structure —
// best measured: 15.78 us. R8 redundant-fusion and R10/R11 spin-fusion both
// regressed; ~10 us of the total is 2-dispatch graph overhead, K1 ~1.5-2 us,
// K2 ~3.5-4 us.)
// K1 (8 blocks x 512 thr): depths (all) + heavy math (wave 0, 1 thr/gaussian)
//   + 8-way-split stable rank; writes sorted 16-float records:
//   [my,c2,L2,c1] [mx,p00,A,B] [C,opn,r,g] [b,-,-,-]
//   where alpha>=eps  <=>  p00*(dx+c1*dy)^2 + c2*dy^2 <= L2  (eps=1e-7).
// K2 (512 blocks x 512 thr): 64x2 row-pair tile per block. Stage records to
//   LDS once; wave w owns chunk w: exact ellipse test vs {row0,row1} ->
//   ballot -> COMPACTED hit list -> pipelined broadcast-LDS eval feeding
//   BOTH rows (shared dx/loads, 2 independent T-chains). 8 chunk partials
//   per row merged with the associative over op; coalesced store.

constexpr int   REC   = 16;     // floats per sorted record (64B)
constexpr int   WIMG  = 256;
constexpr int   HIMG  = 256;
constexpr int   SPLIT = 8;
constexpr float LOG2E  = 1.4426950408889634f;
constexpr float INV2PI = 0.15915494309189535f;
constexpr float INVEPS = 1.0e7f;                // 1/eps, eps = 1e-7 cull

__global__ __launch_bounds__(512) void gs_preprocess(
    const float* __restrict__ means3D, const float* __restrict__ covs3d,
    const float* __restrict__ colors,  const float* __restrict__ opac,
    const float* __restrict__ Km,      const float* __restrict__ Rm,
    const float* __restrict__ tvec,    float* __restrict__ recs, int N)
{
    __shared__ float s_depth[512];
    __shared__ int   s_cnt[64][9];          // [gaussian][partial], padded
    const int t  = threadIdx.x;
    const int l  = t & 63, p = t >> 6;
    const int gi = (int)blockIdx.x * 64 + l;

    // Phase A: all threads -> depth of slot t (pad +inf)
    float d_all = 3.0e38f;
    if (t < N) {
        const float m0 = means3D[t*3+0], m1 = means3D[t*3+1], m2 = means3D[t*3+2];
        d_all = fmaxf(Rm[6]*m0 + Rm[7]*m1 + Rm[8]*m2 + tvec[2], 1.0f);
    }
    s_depth[t] = d_all;
    __syncthreads();

    // Phase B: 8-way split stable rank partial for gaussian gi
    const float dg = s_depth[gi & 511];
    int cnt = 0;
    #pragma unroll 16
    for (int j = p*64; j < p*64 + 64; ++j) {
        const float dj = s_depth[j];
        cnt += (dj < dg) || (dj == dg && j < gi);
    }
    s_cnt[l][p] = cnt;

    // Phase C: heavy per-gaussian math on p==0 threads
    float rec[13];
    const bool act = (p == 0) && (gi < N);
    if (act) {
        float Kl[9], Rl[9], tl[3];
        #pragma unroll
        for (int k = 0; k < 9; ++k) { Kl[k] = Km[k]; Rl[k] = Rm[k]; }
        tl[0] = tvec[0]; tl[1] = tvec[1]; tl[2] = tvec[2];

        const float m0 = means3D[gi*3+0], m1 = means3D[gi*3+1], m2 = means3D[gi*3+2];
        const float cam0 = Rl[0]*m0 + Rl[1]*m1 + Rl[2]*m2 + tl[0];
        const float cam1 = Rl[3]*m0 + Rl[4]*m1 + Rl[5]*m2 + tl[1];
        const float cam2 = Rl[6]*m0 + Rl[7]*m1 + Rl[8]*m2 + tl[2];
        const float Z = cam2;
        const float depth = fmaxf(Z, 1.0f);

        const float s0 = Kl[0]*cam0 + Kl[1]*cam1 + Kl[2]*cam2;
        const float s1 = Kl[3]*cam0 + Kl[4]*cam1 + Kl[5]*cam2;
        const float s2 = Kl[6]*cam0 + Kl[7]*cam1 + Kl[8]*cam2;
        const float mx = s0 / s2, my = s1 / s2;

        const float fx = Kl[0], fy = Kl[4];
        const float iz = 1.0f / Z;
        float J[2][3];
        J[0][0] = fx*iz; J[0][1] = 0.0f;  J[0][2] = -fx*cam0*iz*iz;
        J[1][0] = 0.0f;  J[1][1] = fy*iz; J[1][2] = -fy*cam1*iz*iz;

        float S[9];
        #pragma unroll
        for (int k = 0; k < 9; ++k) S[k] = covs3d[gi*9+k];

        float RS[9], Cc[9];
        #pragma unroll
        for (int r = 0; r < 3; ++r)
            #pragma unroll
            for (int c = 0; c < 3; ++c)
                RS[r*3+c] = Rl[r*3+0]*S[0+c] + Rl[r*3+1]*S[3+c] + Rl[r*3+2]*S[6+c];
        #pragma unroll
        for (int r = 0; r < 3; ++r)
            #pragma unroll
            for (int c = 0; c < 3; ++c)
                Cc[r*3+c] = RS[r*3+0]*Rl[c*3+0] + RS[r*3+1]*Rl[c*3+1] + RS[r*3+2]*Rl[c*3+2];

        float JC[2][3];
        #pragma unroll
        for (int r = 0; r < 2; ++r)
            #pragma unroll
            for (int c = 0; c < 3; ++c)
                JC[r][c] = J[r][0]*Cc[0+c] + J[r][1]*Cc[3+c] + J[r][2]*Cc[6+c];

        const float c200 = JC[0][0]*J[0][0] + JC[0][1]*J[0][1] + JC[0][2]*J[0][2] + 1e-4f;
        const float c201 = JC[0][0]*J[1][0] + JC[0][1]*J[1][1] + JC[0][2]*J[1][2];
        const float c210 = JC[1][0]*J[0][0] + JC[1][1]*J[0][1] + JC[1][2]*J[0][2];
        const float c211 = JC[1][0]*J[1][0] + JC[1][1]*J[1][1] + JC[1][2]*J[1][2] + 1e-4f;

        const float det  = c200*c211 - c201*c210;
        const float idet = 1.0f / det;
        const float ia   = c211*idet;                    // P00
        const float i01  = -0.5f*(c201 + c210)*idet;     // P01 (symmetrized)
        const float ic   = c200*idet;                    // P11
        const float ibs  = 2.0f*i01;

        const bool  valid = (depth > 1.0f) && (depth < 50.0f);
        const float nrm   = valid ? (INV2PI / sqrtf(det)) : 0.0f;
        const float opn   = opac[gi] * nrm;

        // Exact support test params: Q = ia*(dx+c1*dy)^2 + c2*dy^2 <= L2
        const float c1 = i01 / ia;
        const float c2 = ic - i01*i01/ia;
        const float L2 = 2.0f * logf(opn * INVEPS);      // opn<=0 -> -inf

        rec[0]  = my;  rec[1] = c2;  rec[2] = L2;  rec[3] = c1;
        rec[4]  = mx;  rec[5] = ia;
        rec[6]  = -0.5f*LOG2E*ia;    // A
        rec[7]  = -0.5f*LOG2E*ibs;   // B
        rec[8]  = -0.5f*LOG2E*ic;    // C
        rec[9]  = opn;
        rec[10] = colors[gi*3+0];
        rec[11] = colors[gi*3+1];
        rec[12] = colors[gi*3+2];
    }
    __syncthreads();

    if (act) {
        int rank = 0;
        #pragma unroll
        for (int q = 0; q < 8; ++q) rank += s_cnt[l][q];
        float4* dst = (float4*)(recs + rank*REC);
        dst[0] = make_float4(rec[0],  rec[1],  rec[2],  rec[3]);
        dst[1] = make_float4(rec[4],  rec[5],  rec[6],  rec[7]);
        dst[2] = make_float4(rec[8],  rec[9],  rec[10], rec[11]);
        dst[3] = make_float4(rec[12], 0.0f,    0.0f,    0.0f);
    }
}

// Block: 512 thr = 8 waves; 64x2 row-pair tile. Records LDS-staged once.
__global__ __launch_bounds__(512, 4) void gs_render(
    const float* __restrict__ recs, float* __restrict__ out, int N)
{
    __shared__ float  s_my[512], s_c2[512], s_L2[512], s_c1[512], s_mx[512], s_p0[512];
    __shared__ float  s_ev[512][12];          // 48B rows (16B-aligned)
    __shared__ int    s_hits[SPLIT][64];      // compacted hit indices per wave
    __shared__ float4 s_part[2][SPLIT][64];   // [row][chunk][pixel]
    __shared__ float  s_rgb[2][192];

    const int t = threadIdx.x;

    // Stage: thread t handles record t.
    if (t < N) {
        const float4 a = *(const float4*)(recs + t*REC + 0);   // my,c2,L2,c1
        const float4 b = *(const float4*)(recs + t*REC + 4);   // mx,p00,A,B
        const float4 c = *(const float4*)(recs + t*REC + 8);   // C,opn,r,g
        const float4 d = *(const float4*)(recs + t*REC + 12);  // b,-,-,-
        s_my[t] = a.x; s_c2[t] = a.y; s_L2[t] = a.z; s_c1[t] = a.w;
        s_mx[t] = b.x; s_p0[t] = b.y;
        float4* ev = (float4*)s_ev[t];
        ev[0] = make_float4(b.x, a.x, b.z, b.w);   // mx, my, A, B
        ev[1] = make_float4(c.x, c.y, c.z, c.w);   // C, opn, r, g
        s_ev[t][8] = d.x;                          // blue
    } else {
        s_my[t] = 0.0f; s_c2[t] = 0.0f; s_L2[t] = -1e30f;
        s_c1[t] = 0.0f; s_mx[t] = 0.0f; s_p0[t] = 1.0f;
    }
    __syncthreads();

    const int w    = t >> 6;
    const int lane = t & 63;
    const int xs   = (int)blockIdx.x & 3;
    const int pr   = (int)blockIdx.x >> 2;             // row pair 0..127
    const float y0f = (float)(2*pr);
    const float sx0 = (float)(xs * 64);
    const float scx = sx0 + 31.5f;                     // strip center x
    const float px  = sx0 + (float)lane;

    // Lane-parallel EXACT ellipse test vs rows {y0, y0+1} for chunk w.
    const int base = w * 64;
    bool hit;
    {
        const int j = base + lane;
        const float myj = s_my[j], c2 = s_c2[j], L2 = s_L2[j];
        const float c1  = s_c1[j], mxj = s_mx[j], p0 = s_p0[j];
        float dy  = y0f - myj;
        float rem = fmaf(-c2, dy*dy, L2);
        float xc  = fmaf(-c1, dy, mxj);
        float t1  = fmaxf(fabsf(xc - scx) - 31.5f, 0.0f);
        const bool h0 = (p0*t1*t1 <= rem);
        dy  = dy + 1.0f;
        rem = fmaf(-c2, dy*dy, L2);
        xc  = xc - c1;
        t1  = fmaxf(fabsf(xc - scx) - 31.5f, 0.0f);
        const bool h1 = (p0*t1*t1 <= rem);
        hit = h0 | h1;
    }
    const unsigned long long mask = __ballot(hit);
    const int nhit = __popcll(mask);
    if (hit) {
        const int pos = __popcll(mask & ((1ull << lane) - 1ull));
        s_hits[w][pos] = base + lane;     // ascending = sorted depth order
    }
    // s_hits[w] written & read by the same wave only: no barrier needed.

    float T0 = 1.0f, r0 = 0.0f, g0 = 0.0f, b0 = 0.0f;
    float T1 = 1.0f, r1 = 0.0f, g1 = 0.0f, b1 = 0.0f;

    for (int i = 0; i < nhit; ++i) {
        const int j = s_hits[w][i];                  // broadcast read
        const float* e = s_ev[j];                    // broadcast rows
        const float4 v0 = *(const float4*)(e + 0);   // mx,my,A,B
        const float4 v1 = *(const float4*)(e + 4);   // C,opn,r,g
        const float  bl = e[8];

        const float dx   = px - v0.x;
        const float adx2 = v0.z * dx * dx;           // A*dx^2 (shared)
        const float u    = v0.w * dx;                // B*dx   (shared)
        const float dy0  = y0f - v0.y;
        const float dy1  = dy0 + 1.0f;
        const float e20  = fmaf(dy0, fmaf(v1.x, dy0, u), adx2);
        const float e21  = fmaf(dy1, fmaf(v1.x, dy1, u), adx2);
        const float al0  = v1.y * __builtin_amdgcn_exp2f(e20);
        const float al1  = v1.y * __builtin_amdgcn_exp2f(e21);

        T0 *= (1.0f - al0);                          // cumprod incl. current
        const float w0 = al0 * T0;
        r0 = fmaf(w0, v1.z, r0); g0 = fmaf(w0, v1.w, g0); b0 = fmaf(w0, bl, b0);

        T1 *= (1.0f - al1);
        const float w1 = al1 * T1;
        r1 = fmaf(w1, v1.z, r1); g1 = fmaf(w1, v1.w, g1); b1 = fmaf(w1, bl, b1);
    }

    s_part[0][w][lane] = make_float4(T0, r0, g0, b0);
    s_part[1][w][lane] = make_float4(T1, r1, g1, b1);
    __syncthreads();

    if (t < 128) {
        const int row = t >> 6, p = t & 63;
        float4 f = s_part[row][0][p];
        float Ta = f.x, r_ = f.y, g_ = f.z, b_ = f.w;
        #pragma unroll
        for (int k = 1; k < SPLIT; ++k) {
            const float4 q = s_part[row][k][p];
            r_ = fmaf(Ta, q.y, r_);
            g_ = fmaf(Ta, q.z, g_);
            b_ = fmaf(Ta, q.w, b_);
            Ta *= q.x;
        }
        s_rgb[row][p*3+0] = r_;
        s_rgb[row][p*3+1] = g_;
        s_rgb[row][p*3+2] = b_;
    }
    __syncthreads();

    if (t < 384) {
        const int row = t / 192, i = t - row * 192;
        out[(2*pr + row) * (WIMG*3) + xs*192 + i] = s_rgb[row][i];
    }
}

extern "C" void kernel_launch(void* const* d_in, const int* in_sizes, int n_in,
                              void* d_out, int out_size, void* d_ws, size_t ws_size,
                              hipStream_t stream)
{
    const float* means3D = (const float*)d_in[0];
    const float* covs3d  = (const float*)d_in[1];
    const float* colors  = (const float*)d_in[2];
    const float* opac    = (const float*)d_in[3];
    const float* Km      = (const float*)d_in[4];
    const float* Rm      = (const float*)d_in[5];
    const float* tv      = (const float*)d_in[6];
    const int N = in_sizes[3];               // opacities: (N,)

    float* recs = (float*)d_ws;              // N*REC floats = 32 KB
    float* out  = (float*)d_out;

    gs_preprocess<<<dim3((N + 63) / 64), dim3(512), 0, stream>>>(
        means3D, covs3d, colors, opac, Km, Rm, tv, recs, N);

    gs_render<<<dim3(WIMG * HIMG / 128), dim3(512), 0, stream>>>(recs, out, N);
}